// Round 4
// baseline (541.258 us; speedup 1.0000x reference)
//
#include <hip/hip_runtime.h>
#include <math.h>

#define BATCH   262144
#define CLUSTER 100

// Analytic Lorentz boost matrix B = I - (g*mag)*nK + (g-1)*nK^2:
//   B[0][0]     = g
//   B[0][j+1]   = B[j+1][0] = -(g*mag)*n_j
//   B[i+1][j+1] = delta_ij + (g-1)*n_i*n_j
__device__ inline void boost_mat(float bx, float by, float bz, float B[4][4]) {
    float m2  = bx * bx + by * by + bz * bz;
    float mag = sqrtf(m2);
    float nx = bx / mag, ny = by / mag, nz = bz / mag;
    float g  = 1.0f / sqrtf(1.0f - mag * mag);
    float gm = g * mag;
    float gm1 = g - 1.0f;
    float n[3] = {nx, ny, nz};
    B[0][0] = 1.0f + gm1 * (nx * nx + ny * ny + nz * nz);
    for (int j = 0; j < 3; ++j) {
        B[0][j + 1] = -gm * n[j];
        B[j + 1][0] = -gm * n[j];
    }
    for (int i = 0; i < 3; ++i)
        for (int j = 0; j < 3; ++j)
            B[i + 1][j + 1] = ((i == j) ? 1.0f : 0.0f) + gm1 * n[i] * n[j];
}

#define DOT4(mm, vv) ((mm).x*(vv).x + (mm).y*(vv).y + (mm).z*(vv).z + (mm).w*(vv).w)

// out[b][a] = sum_c sum_d M[c][a][d] * T[b][c][d],  M_c = BiM @ (W_c * BoM_c)
// 8-lane group: lane q handles clusters c = 8t+q  -> full 128B line per row per
// load instruction. Each group owns rows (base+g, base+g+8): 16 rows per wave.
// t=0 loads are issued BEFORE the M-build so HBM latency hides the build.
// Results are shuffle-packed so lanes 0..15 store 256B fully contiguous.
__global__ __launch_bounds__(256, 6) void lorentz_fused_kernel(
        const float* __restrict__ T,
        const float* __restrict__ Bo,
        const float* __restrict__ Bi,
        const float* __restrict__ W,
        float* __restrict__ out) {
    __shared__ float sM[CLUSTER * 16];

    int tid  = threadIdx.x;
    int wave = tid >> 6;
    int lane = tid & 63;
    int q = lane & 7;       // position in 8-lane group
    int g = lane >> 3;      // group 0..7
    long long base = (long long)blockIdx.x * 64 + wave * 16;

    const float* P0 = T + (base + g)     * (CLUSTER * 4);
    const float* P1 = T + (base + g + 8) * (CLUSTER * 4);

    // --- issue t=0 global loads first: in flight during the M build ---
    float4 v0 = *(const float4*)(P0 + q * 4);
    float4 v1 = *(const float4*)(P1 + q * 4);

    // --- build all 100 M_c matrices in-block ---
    if (tid < CLUSTER) {
        float BiM[4][4], BoM[4][4];
        boost_mat(Bi[0], Bi[1], Bi[2], BiM);
        boost_mat(Bo[tid * 3 + 0], Bo[tid * 3 + 1], Bo[tid * 3 + 2], BoM);
        float w = W[tid];
        for (int a = 0; a < 4; ++a)
            for (int d = 0; d < 4; ++d) {
                float s = 0.0f;
                for (int e = 0; e < 4; ++e)
                    s += BiM[a][e] * (w * BoM[e][d]);
                sM[tid * 16 + a * 4 + d] = s;
            }
    }
    __syncthreads();

    float4 a0 = {0.f, 0.f, 0.f, 0.f};
    float4 a1 = a0;

    // 12 full steps (c = 8t+q), rotating prefetch; tail c=96..99 on lanes q<4.
    #pragma unroll
    for (int t = 0; t < 12; ++t) {
        float4 n0, n1;
        if (t < 11) {
            int cn = 8 * (t + 1) + q;
            n0 = *(const float4*)(P0 + cn * 4);
            n1 = *(const float4*)(P1 + cn * 4);
        } else if (q < 4) {            // prefetch tail clusters 96..99
            int cn = 96 + q;
            n0 = *(const float4*)(P0 + cn * 4);
            n1 = *(const float4*)(P1 + cn * 4);
        }
        int c = 8 * t + q;
        const float4* m = (const float4*)(sM + c * 16);
        float4 m0 = m[0], m1 = m[1], m2 = m[2], m3 = m[3];
        a0.x += DOT4(m0, v0); a0.y += DOT4(m1, v0); a0.z += DOT4(m2, v0); a0.w += DOT4(m3, v0);
        a1.x += DOT4(m0, v1); a1.y += DOT4(m1, v1); a1.z += DOT4(m2, v1); a1.w += DOT4(m3, v1);
        v0 = n0; v1 = n1;
    }
    if (q < 4) {                       // tail compute, c = 96+q
        int c = 96 + q;
        const float4* m = (const float4*)(sM + c * 16);
        float4 m0 = m[0], m1 = m[1], m2 = m[2], m3 = m[3];
        a0.x += DOT4(m0, v0); a0.y += DOT4(m1, v0); a0.z += DOT4(m2, v0); a0.w += DOT4(m3, v0);
        a1.x += DOT4(m0, v1); a1.y += DOT4(m1, v1); a1.z += DOT4(m2, v1); a1.w += DOT4(m3, v1);
    }

    // butterfly reduce across the 8-lane group; all lanes end with full sums
    #define RED(f) f += __shfl_xor(f, 1); f += __shfl_xor(f, 2); f += __shfl_xor(f, 4);
    RED(a0.x) RED(a0.y) RED(a0.z) RED(a0.w)
    RED(a1.x) RED(a1.y) RED(a1.z) RED(a1.w)
    #undef RED

    // pack: lane t<8 takes a0 of group t, lane 8<=t<16 takes a1 of group t-8,
    // then lanes 0..15 store 256B fully contiguous (full cache lines).
    int src = (lane & 7) * 8;
    float4 w0, w1;
    w0.x = __shfl(a0.x, src); w0.y = __shfl(a0.y, src);
    w0.z = __shfl(a0.z, src); w0.w = __shfl(a0.w, src);
    w1.x = __shfl(a1.x, src); w1.y = __shfl(a1.y, src);
    w1.z = __shfl(a1.z, src); w1.w = __shfl(a1.w, src);
    float4 o = (lane < 8) ? w0 : w1;
    if (lane < 16)
        ((float4*)out)[base + lane] = o;
}

extern "C" void kernel_launch(void* const* d_in, const int* in_sizes, int n_in,
                              void* d_out, int out_size, void* d_ws, size_t ws_size,
                              hipStream_t stream) {
    const float* T  = (const float*)d_in[0];
    const float* Bo = (const float*)d_in[1];
    const float* Bi = (const float*)d_in[2];
    const float* W  = (const float*)d_in[3];
    // d_in[4] = K_mats (folded into analytic boost formula)

    float* out = (float*)d_out;

    int blocks = BATCH / 64;   // 64 rows per block (4 waves x 16 rows)
    lorentz_fused_kernel<<<blocks, 256, 0, stream>>>(T, Bo, Bi, W, out);
}

// Round 5
// 82.905 us; speedup vs baseline: 6.5287x; 6.5287x over previous
//
#include <hip/hip_runtime.h>
#include <math.h>

#define BATCH   262144
#define CLUSTER 100

// Analytic Lorentz boost matrix B = I - (g*mag)*nK + (g-1)*nK^2:
//   B[0][0]     = g
//   B[0][j+1]   = B[j+1][0] = -(g*mag)*n_j
//   B[i+1][j+1] = delta_ij + (g-1)*n_i*n_j
__device__ inline void boost_mat(float bx, float by, float bz, float B[4][4]) {
    float m2  = bx * bx + by * by + bz * bz;
    float mag = sqrtf(m2);
    float nx = bx / mag, ny = by / mag, nz = bz / mag;
    float g  = 1.0f / sqrtf(1.0f - mag * mag);
    float gm = g * mag;
    float gm1 = g - 1.0f;
    float n[3] = {nx, ny, nz};
    B[0][0] = 1.0f + gm1 * (nx * nx + ny * ny + nz * nz);
    for (int j = 0; j < 3; ++j) {
        B[0][j + 1] = -gm * n[j];
        B[j + 1][0] = -gm * n[j];
    }
    for (int i = 0; i < 3; ++i)
        for (int j = 0; j < 3; ++j)
            B[i + 1][j + 1] = ((i == j) ? 1.0f : 0.0f) + gm1 * n[i] * n[j];
}

#define DOT4(mm, vv) ((mm).x*(vv).x + (mm).y*(vv).y + (mm).z*(vv).z + (mm).w*(vv).w)

// out[b][a] = sum_c sum_d M[c][a][d] * T[b][c][d],  M_c = BiM @ (W_c * BoM_c)
// 16-lane group: lane q handles clusters c = 16t+q -> each load instruction
// covers 4 x 256B fully-contiguous segments. Group owns 4 rows
// (base+g+4r, r=0..3): 16 rows per wave, 64 per block.
// M stored SoA: sMr[a][c*4+d] -> start bank (16a+4q)%32, no >2-way conflicts.
__global__ __launch_bounds__(256) void lorentz_fused_kernel(
        const float* __restrict__ T,
        const float* __restrict__ Bo,
        const float* __restrict__ Bi,
        const float* __restrict__ W,
        float* __restrict__ out) {
    __shared__ float sMr[4][CLUSTER * 4];

    int tid  = threadIdx.x;
    int wave = tid >> 6;
    int lane = tid & 63;
    int q = lane & 15;      // position in 16-lane group
    int g = lane >> 4;      // group 0..3
    long long base = (long long)blockIdx.x * 64 + wave * 16;

    const float* P0 = T + (base + g +  0) * (CLUSTER * 4);
    const float* P1 = T + (base + g +  4) * (CLUSTER * 4);
    const float* P2 = T + (base + g +  8) * (CLUSTER * 4);
    const float* P3 = T + (base + g + 12) * (CLUSTER * 4);

    // issue t=0 loads first: in flight during the M build
    float4 v0 = *(const float4*)(P0 + q * 4);
    float4 v1 = *(const float4*)(P1 + q * 4);
    float4 v2 = *(const float4*)(P2 + q * 4);
    float4 v3 = *(const float4*)(P3 + q * 4);

    // build all 100 M_c matrices in-block, SoA layout
    if (tid < CLUSTER) {
        float BiM[4][4], BoM[4][4];
        boost_mat(Bi[0], Bi[1], Bi[2], BiM);
        boost_mat(Bo[tid * 3 + 0], Bo[tid * 3 + 1], Bo[tid * 3 + 2], BoM);
        float w = W[tid];
        for (int a = 0; a < 4; ++a)
            for (int d = 0; d < 4; ++d) {
                float s = 0.0f;
                for (int e = 0; e < 4; ++e)
                    s += BiM[a][e] * (w * BoM[e][d]);
                sMr[a][tid * 4 + d] = s;
            }
    }
    __syncthreads();

    float4 a0 = {0.f, 0.f, 0.f, 0.f};
    float4 a1 = a0, a2 = a0, a3 = a0;

    #define ACCSTEP(c)                                                        \
    {                                                                         \
        float4 m0 = *(const float4*)&sMr[0][(c) * 4];                         \
        float4 m1 = *(const float4*)&sMr[1][(c) * 4];                         \
        float4 m2 = *(const float4*)&sMr[2][(c) * 4];                         \
        float4 m3 = *(const float4*)&sMr[3][(c) * 4];                         \
        a0.x += DOT4(m0, v0); a0.y += DOT4(m1, v0); a0.z += DOT4(m2, v0); a0.w += DOT4(m3, v0); \
        a1.x += DOT4(m0, v1); a1.y += DOT4(m1, v1); a1.z += DOT4(m2, v1); a1.w += DOT4(m3, v1); \
        a2.x += DOT4(m0, v2); a2.y += DOT4(m1, v2); a2.z += DOT4(m2, v2); a2.w += DOT4(m3, v2); \
        a3.x += DOT4(m0, v3); a3.y += DOT4(m1, v3); a3.z += DOT4(m2, v3); a3.w += DOT4(m3, v3); \
    }

    // 6 full steps (c = 16t+q covers 0..95), prefetch depth 1; tail c=96..99.
    for (int t = 0; t < 6; ++t) {
        int c = 16 * t + q;
        ACCSTEP(c)
        if (t < 5) {
            int cn = c + 16;
            v0 = *(const float4*)(P0 + cn * 4);
            v1 = *(const float4*)(P1 + cn * 4);
            v2 = *(const float4*)(P2 + cn * 4);
            v3 = *(const float4*)(P3 + cn * 4);
        } else if (q < 4) {
            int cn = 96 + q;
            v0 = *(const float4*)(P0 + cn * 4);
            v1 = *(const float4*)(P1 + cn * 4);
            v2 = *(const float4*)(P2 + cn * 4);
            v3 = *(const float4*)(P3 + cn * 4);
        }
    }
    if (q < 4) {
        ACCSTEP(96 + q)
    }
    #undef ACCSTEP

    // butterfly reduce across the 16-lane group; all lanes end with full sums
    #define RED(f) f += __shfl_xor(f, 1); f += __shfl_xor(f, 2); \
                   f += __shfl_xor(f, 4); f += __shfl_xor(f, 8);
    RED(a0.x) RED(a0.y) RED(a0.z) RED(a0.w)
    RED(a1.x) RED(a1.y) RED(a1.z) RED(a1.w)
    RED(a2.x) RED(a2.y) RED(a2.z) RED(a2.w)
    RED(a3.x) RED(a3.y) RED(a3.z) RED(a3.w)
    #undef RED

    // lane q<4 stores accumulator a_q at row base+g+4q; wave covers 256B.
    float4 o = a0;
    if (q == 1) o = a1;
    if (q == 2) o = a2;
    if (q == 3) o = a3;
    if (q < 4)
        ((float4*)out)[base + g + 4 * q] = o;
}

extern "C" void kernel_launch(void* const* d_in, const int* in_sizes, int n_in,
                              void* d_out, int out_size, void* d_ws, size_t ws_size,
                              hipStream_t stream) {
    const float* T  = (const float*)d_in[0];
    const float* Bo = (const float*)d_in[1];
    const float* Bi = (const float*)d_in[2];
    const float* W  = (const float*)d_in[3];
    // d_in[4] = K_mats (folded into analytic boost formula)

    float* out = (float*)d_out;

    int blocks = BATCH / 64;   // 64 rows per block (4 waves x 16 rows)
    lorentz_fused_kernel<<<blocks, 256, 0, stream>>>(T, Bo, Bi, W, out);
}